// Round 10
// baseline (178.198 us; speedup 1.0000x reference)
//
#include <hip/hip_runtime.h>
#include <hip/hip_bf16.h>

// GAT layer: B=8, N=8 (BN=64 batches), Nodes=512, IF=OF=256.
// MFMA on v_mfma_f32_16x16x32_bf16, split-bf16 (hi+lo) operands.
//
// r10: single-variable change vs r9 — the PV softmax is rewritten from
// serial-8-rows-per-wave to ALL-ROWS-PARALLEL (row = tid>>3, 8 lanes/row,
// 3-deep shuffle reduce, 2-pass max/exp). P stored UN-normalized in the same
// swizzled LDS image; normalization via rowinv[] in the epilogue. GEMM loop,
// wh_gemm, detect, prep are byte-identical to r9 (clean ablation of softmax).

#define ALPHA 0.2f
#define MASK_VAL -9000000000000000.0f
#define NODES 512
#define FDIM 256
#define BN 64

typedef float  f32x4 __attribute__((ext_vector_type(4)));
typedef int    i32x4 __attribute__((ext_vector_type(4)));
typedef short  s16x8 __attribute__((ext_vector_type(8)));
typedef short  s16x4 __attribute__((ext_vector_type(4)));
typedef __bf16 bf16x8 __attribute__((ext_vector_type(8)));

__device__ __forceinline__ unsigned short f2bfu(float x) {
    __hip_bfloat16 b = __float2bfloat16(x);   // RNE
    unsigned short u; __builtin_memcpy(&u, &b, 2); return u;
}
__device__ __forceinline__ float bfu2f(unsigned short u) {
    unsigned int w = ((unsigned int)u) << 16; return __uint_as_float(w);
}
__device__ __forceinline__ f32x4 mfma16(s16x8 a, s16x8 b, f32x4 c) {
    return __builtin_amdgcn_mfma_f32_16x16x32_bf16(
        __builtin_bit_cast(bf16x8, a), __builtin_bit_cast(bf16x8, b), c, 0, 0, 0);
}

// hi/lo split of 8 fp32 (truncation split; residual ~2^-16 rel).
__device__ __forceinline__ void split8v(f32x4 v0, f32x4 v1, s16x8& hi, s16x8& lo)
{
    float x[8] = {v0[0], v0[1], v0[2], v0[3], v1[0], v1[1], v1[2], v1[3]};
    unsigned hw[4], lw[4];
    #pragma unroll
    for (int d = 0; d < 4; ++d) {
        const unsigned u0 = __float_as_uint(x[2*d]);
        const unsigned u1 = __float_as_uint(x[2*d + 1]);
        hw[d] = __builtin_amdgcn_perm(u1, u0, 0x07060302);
        const float l0 = x[2*d]     - __uint_as_float(u0 & 0xFFFF0000u);
        const float l1 = x[2*d + 1] - __uint_as_float(u1 & 0xFFFF0000u);
        lw[d] = __builtin_amdgcn_perm(__float_as_uint(l1), __float_as_uint(l0),
                                      0x07060302);
    }
    hi = __builtin_bit_cast(s16x8, *(unsigned(*)[4])hw);
    lo = __builtin_bit_cast(s16x8, *(unsigned(*)[4])lw);
}

__device__ __forceinline__ void gll16(const void* g, void* l) {
    __builtin_amdgcn_global_load_lds(
        (const __attribute__((address_space(1))) unsigned int*)g,
        (__attribute__((address_space(3))) unsigned int*)l,
        16, 0, 0);
}

// ---------------- K0: dtype detect ----------------
__global__ __launch_bounds__(256) void detect_kernel(const unsigned short* __restrict__ hraw,
                                                     int* __restrict__ flag)
{
    const int tid = threadIdx.x;
    float m = 0.0f;
    for (int i = tid; i < 16384; i += 256) {
        unsigned int w = ((unsigned int)hraw[i]) << 16;
        float v = __uint_as_float(w);
        v = fabsf(v);
        if (!(v == v)) v = 1e30f;
        m = fmaxf(m, v);
    }
    #pragma unroll
    for (int off = 32; off >= 1; off >>= 1)
        m = fmaxf(m, __shfl_down(m, off));
    __shared__ float red[4];
    if ((tid & 63) == 0) red[tid >> 6] = m;
    __syncthreads();
    if (tid == 0) {
        float mm = fmaxf(fmaxf(red[0], red[1]), fmaxf(red[2], red[3]));
        *flag = (mm > 1e4f) ? 1 : 0;
    }
}

// ---------------- KP: W -> Wt[f][k] bf16 hi/lo ----------------
__global__ __launch_bounds__(256) void prep_w_kernel(
    const void* __restrict__ Wv, const int* __restrict__ flagp,
    short* __restrict__ WtHi, short* __restrict__ WtLo)
{
    const int flag = *flagp;
    __shared__ float tile[16][17];
    const int tx = threadIdx.x & 15, ty = threadIdx.x >> 4;
    const int kk = blockIdx.y * 16 + ty;
    const int f  = blockIdx.x * 16 + tx;
    float v;
    if (flag) v = ((const float*)Wv)[kk * FDIM + f];
    else      v = bfu2f(((const unsigned short*)Wv)[kk * FDIM + f]);
    tile[ty][tx] = v;
    __syncthreads();
    const float x = tile[tx][ty];
    const int fo = blockIdx.x * 16 + ty;
    const int ko = blockIdx.y * 16 + tx;
    unsigned short h = f2bfu(x);
    WtHi[fo * FDIM + ko] = (short)h;
    WtLo[fo * FDIM + ko] = (short)f2bfu(x - bfu2f(h));  // exact 0 in bf16 mode
}

// ---------------- KA: Wh = h@W ----------------
// 512 blocks x 512 thr (8 waves; LDS 68K -> 2 blocks/CU, 16 waves/CU).
// Wave w owns cols [w*32, w*32+32). A panel (64x256 hi/lo) in LDS.
// K-loop barrier-free; B via depth-2 register pipeline from global (L2).
__global__ __launch_bounds__(512, 4) void wh_gemm(
    const void* __restrict__ hv,
    const short* __restrict__ WtHi, const short* __restrict__ WtLo,
    const void* __restrict__ av, const int* __restrict__ flagp,
    short* __restrict__ WhTHi, short* __restrict__ WhTLo,
    float* __restrict__ srcv, float* __restrict__ dstv)
{
    __shared__ __align__(16) char smem[69632];  // A hi 32K | A lo 32K | red 4K

    const int flag = *flagp;
    const int blk = blockIdx.x;
    const int bn  = blk >> 3;
    const int i0  = (blk & 7) * 64;
    const size_t r0g = (size_t)blk * 64;
    const int tid = threadIdx.x;
    const int w = tid >> 6, l = tid & 63;
    const int fb = l & 15, g = l >> 4;

    // ---- stage A panel once ----
    if (flag) {
        const int srow = tid >> 3, q = tid & 7;   // 8 threads per row
        const float* gA = (const float*)hv + (r0g + srow) * FDIM;
        #pragma unroll
        for (int i = 0; i < 4; ++i) {
            const int seg = q + 8 * i;
            f32x4 v0 = *(const f32x4*)(gA + seg * 8);
            f32x4 v1 = *(const f32x4*)(gA + seg * 8 + 4);
            s16x8 hi, lo; split8v(v0, v1, hi, lo);
            const int slot = seg ^ (srow & 7);
            *(s16x8*)(smem + srow * 512 + slot * 16) = hi;
            *(s16x8*)(smem + 32768 + srow * 512 + slot * 16) = lo;
        }
    } else {
        const short* hs = (const short*)hv;
        const unsigned wub = (unsigned)(tid & ~63);
        #pragma unroll
        for (int i = 0; i < 4; ++i) {
            const int idx = i * 512 + tid;        // 0..2047
            const int row = idx >> 5, slot = idx & 31;
            const int srcseg = slot ^ (row & 7);
            gll16(hs + (r0g + row) * FDIM + srcseg * 8,
                  smem + (i * 512 + (int)wub) * 16);
        }
    }
    __syncthreads();   // A panel ready (drains vmcnt + lgkm)

    f32x4 acc[4][2];
    #pragma unroll
    for (int rt = 0; rt < 4; ++rt)
        #pragma unroll
        for (int ct = 0; ct < 2; ++ct) acc[rt][ct] = f32x4{0.f,0.f,0.f,0.f};

    const int f0 = w * 32 + fb;
    const int f1 = f0 + 16;
    const short* gH0 = WtHi + f0 * FDIM + g * 8;
    const short* gH1 = WtHi + f1 * FDIM + g * 8;
    const short* gL0 = WtLo + f0 * FDIM + g * 8;
    const short* gL1 = WtLo + f1 * FDIM + g * 8;

    if (flag) {
        s16x8 pb[3][4];
        #pragma unroll
        for (int d = 0; d < 2; ++d) {
            pb[d][0] = *(const s16x8*)(gH0 + d * 32);
            pb[d][1] = *(const s16x8*)(gH1 + d * 32);
            pb[d][2] = *(const s16x8*)(gL0 + d * 32);
            pb[d][3] = *(const s16x8*)(gL1 + d * 32);
        }
        #pragma unroll
        for (int t = 0; t < 8; ++t) {
            const int cur = t % 3;
            if (t + 2 < 8) {
                const int nx = (t + 2) % 3;
                pb[nx][0] = *(const s16x8*)(gH0 + (t + 2) * 32);
                pb[nx][1] = *(const s16x8*)(gH1 + (t + 2) * 32);
                pb[nx][2] = *(const s16x8*)(gL0 + (t + 2) * 32);
                pb[nx][3] = *(const s16x8*)(gL1 + (t + 2) * 32);
            }
            s16x8 ah[4], al[4];
            #pragma unroll
            for (int rt = 0; rt < 4; ++rt) {
                const int row = rt * 16 + fb;
                const int slot = (t * 4 + g) ^ (row & 7);
                ah[rt] = *(const s16x8*)(smem + row * 512 + slot * 16);
                al[rt] = *(const s16x8*)(smem + 32768 + row * 512 + slot * 16);
            }
            __builtin_amdgcn_s_setprio(1);
            #pragma unroll
            for (int rt = 0; rt < 4; ++rt) {
                acc[rt][0] = mfma16(ah[rt], pb[cur][0], acc[rt][0]);
                acc[rt][0] = mfma16(al[rt], pb[cur][0], acc[rt][0]);
                acc[rt][0] = mfma16(ah[rt], pb[cur][2], acc[rt][0]);
                acc[rt][1] = mfma16(ah[rt], pb[cur][1], acc[rt][1]);
                acc[rt][1] = mfma16(al[rt], pb[cur][1], acc[rt][1]);
                acc[rt][1] = mfma16(ah[rt], pb[cur][3], acc[rt][1]);
            }
            __builtin_amdgcn_s_setprio(0);
        }
    } else {
        s16x8 pb[3][2];
        #pragma unroll
        for (int d = 0; d < 2; ++d) {
            pb[d][0] = *(const s16x8*)(gH0 + d * 32);
            pb[d][1] = *(const s16x8*)(gH1 + d * 32);
        }
        #pragma unroll
        for (int t = 0; t < 8; ++t) {
            const int cur = t % 3;
            if (t + 2 < 8) {
                const int nx = (t + 2) % 3;
                pb[nx][0] = *(const s16x8*)(gH0 + (t + 2) * 32);
                pb[nx][1] = *(const s16x8*)(gH1 + (t + 2) * 32);
            }
            s16x8 ah[4];
            #pragma unroll
            for (int rt = 0; rt < 4; ++rt) {
                const int row = rt * 16 + fb;
                const int slot = (t * 4 + g) ^ (row & 7);
                ah[rt] = *(const s16x8*)(smem + row * 512 + slot * 16);
            }
            __builtin_amdgcn_s_setprio(1);
            #pragma unroll
            for (int rt = 0; rt < 4; ++rt) {
                acc[rt][0] = mfma16(ah[rt], pb[cur][0], acc[rt][0]);
                acc[rt][1] = mfma16(ah[rt], pb[cur][1], acc[rt][1]);
            }
            __builtin_amdgcn_s_setprio(0);
        }
    }

    // Write WhT[bn][f][i] hi/lo. D: row = rt*16 + g*4 + r, col = f.
    const size_t wbT = (size_t)bn * FDIM * NODES;
    #pragma unroll
    for (int rt = 0; rt < 4; ++rt) {
        const int orow = i0 + rt * 16 + g * 4;
        #pragma unroll
        for (int ct = 0; ct < 2; ++ct) {
            const int f = w * 32 + ct * 16 + fb;
            s16x4 h4, l4;
            #pragma unroll
            for (int r = 0; r < 4; ++r) {
                float x = acc[rt][ct][r];
                unsigned short hh = f2bfu(x);
                h4[r] = (short)hh;
                l4[r] = (short)f2bfu(x - bfu2f(hh));
            }
            *(s16x4*)(WhTHi + wbT + (size_t)f * NODES + orow) = h4;
            *(s16x4*)(WhTLo + wbT + (size_t)f * NODES + orow) = l4;
        }
    }

    // src/dst reduction (fp32 accumulator path).
    float a1v[2], a2v[2];
    #pragma unroll
    for (int ct = 0; ct < 2; ++ct) {
        const int f = w * 32 + ct * 16 + fb;
        if (flag) {
            a1v[ct] = ((const float*)av)[f];
            a2v[ct] = ((const float*)av)[FDIM + f];
        } else {
            a1v[ct] = bfu2f(((const unsigned short*)av)[f]);
            a2v[ct] = bfu2f(((const unsigned short*)av)[FDIM + f]);
        }
    }
    float* red1 = (float*)(smem + 65536);   // [8][64]
    float* red2 = (float*)(smem + 67584);   // [8][64]
    #pragma unroll
    for (int rt = 0; rt < 4; ++rt) {
        #pragma unroll
        for (int r = 0; r < 4; ++r) {
            float s1 = 0.f, s2 = 0.f;
            #pragma unroll
            for (int ct = 0; ct < 2; ++ct) {
                s1 = fmaf(acc[rt][ct][r], a1v[ct], s1);
                s2 = fmaf(acc[rt][ct][r], a2v[ct], s2);
            }
            #pragma unroll
            for (int off = 1; off <= 8; off <<= 1) {
                s1 += __shfl_xor(s1, off);
                s2 += __shfl_xor(s2, off);
            }
            if (fb == 0) {
                red1[w * 64 + rt * 16 + g * 4 + r] = s1;
                red2[w * 64 + rt * 16 + g * 4 + r] = s2;
            }
        }
    }
    __syncthreads();
    if (tid < 64) {
        float s1 = 0.f, s2 = 0.f;
        #pragma unroll
        for (int ww = 0; ww < 8; ++ww) {
            s1 += red1[ww * 64 + tid];
            s2 += red2[ww * 64 + tid];
        }
        srcv[bn * NODES + i0 + tid] = s1;
        dstv[bn * NODES + i0 + tid] = s2;
    }
}

// ---------------- KB: fused softmax + att@Wh + elu ----------------
// 512 blocks (XCD-swizzled) x 512 thr (8 waves; LDS ~64K -> 2 blocks/CU).
// NEW softmax: all 64 rows in parallel (row = tid>>3, 8 lanes/row, 64 j's
// per lane, 2-pass, 3-deep shuffle reduce). P stored UN-normalized bf16 in
// swizzled LDS image; epilogue scales by rowinv. GEMM loop = r9 unchanged.
__global__ __launch_bounds__(512, 4) void pv_gemm(
    const short* __restrict__ WhTHi, const short* __restrict__ WhTLo,
    const float* __restrict__ srcv, const float* __restrict__ dstv,
    const int* __restrict__ adj, const int* __restrict__ flagp,
    void* __restrict__ out)
{
    __shared__ __align__(16) char smem[65792];   // Ps 64K | rowinv 256B

    const int flag = *flagp;
    const int b0 = blockIdx.x;
    const int blk = (b0 & 7) * 64 + (b0 >> 3);   // bijective: 512 % 8 == 0
    const int bn  = blk >> 3;
    const int i0  = (blk & 7) * 64;
    const int tid = threadIdx.x;
    const int w = tid >> 6, l = tid & 63;
    float* rowinvS = (float*)(smem + 65536);

    const short* bhig = WhTHi + (size_t)bn * FDIM * NODES;
    const short* blog = WhTLo + (size_t)bn * FDIM * NODES;

    // GEMM addressing (also used to preload B before the softmax barrier).
    const int fb = l & 15, g = l >> 4;
    const int f0 = w * 32 + fb;
    const int f1 = f0 + 16;
    const short* gH0 = bhig + (size_t)f0 * NODES + g * 8;
    const short* gH1 = bhig + (size_t)f1 * NODES + g * 8;
    const short* gL0 = blog + (size_t)f0 * NODES + g * 8;
    const short* gL1 = blog + (size_t)f1 * NODES + g * 8;

    // preload B steps 0,1 (latency hides under softmax; barrier drains them)
    s16x8 pb[3][4];
    #pragma unroll
    for (int d = 0; d < 2; ++d) {
        pb[d][0] = *(const s16x8*)(gH0 + d * 32);
        pb[d][1] = *(const s16x8*)(gH1 + d * 32);
        pb[d][2] = *(const s16x8*)(gL0 + d * 32);
        pb[d][3] = *(const s16x8*)(gL1 + d * 32);
    }

    // ---- softmax: ALL rows parallel. row = tid>>3, sub = tid&7 ----
    {
        const int row = tid >> 3, sub = tid & 7;
        const int* adjrow = adj + (size_t)(i0 + row) * NODES + sub * 64;
        const float* drow = dstv + bn * NODES + sub * 64;
        const float srow = srcv[bn * NODES + i0 + row];

        // pass 1: max over this lane's 64 j's (includes MASK_VAL like ref)
        float m = -3.0e38f;
        #pragma unroll
        for (int c = 0; c < 16; ++c) {
            const i32x4 q = *(const i32x4*)(adjrow + c * 4);
            const f32x4 d = *(const f32x4*)(drow + c * 4);
            #pragma unroll
            for (int e = 0; e < 4; ++e) {
                float ev = srow + d[e];
                ev = (ev > 0.f) ? ev : ALPHA * ev;
                m = fmaxf(m, (q[e] > 0) ? ev : MASK_VAL);
            }
        }
        m = fmaxf(m, __shfl_xor(m, 1));
        m = fmaxf(m, __shfl_xor(m, 2));
        m = fmaxf(m, __shfl_xor(m, 4));

        // pass 2: exp, sum, store un-normalized P (swizzled image)
        float s = 0.f;
        #pragma unroll
        for (int c8 = 0; c8 < 8; ++c8) {
            const i32x4 q0 = *(const i32x4*)(adjrow + c8 * 8);
            const i32x4 q1 = *(const i32x4*)(adjrow + c8 * 8 + 4);
            const f32x4 d0 = *(const f32x4*)(drow + c8 * 8);
            const f32x4 d1 = *(const f32x4*)(drow + c8 * 8 + 4);
            s16x8 ph;
            #pragma unroll
            for (int e = 0; e < 4; ++e) {
                float ev = srow + d0[e];
                ev = (ev > 0.f) ? ev : ALPHA * ev;
                ev = (q0[e] > 0) ? ev : MASK_VAL;
                float p = __expf(ev - m);   // masked -> 0; all-masked row -> 1
                s += p;
                ph[e] = (short)f2bfu(p);
                float ew = srow + d1[e];
                ew = (ew > 0.f) ? ew : ALPHA * ew;
                ew = (q1[e] > 0) ? ew : MASK_VAL;
                float p2 = __expf(ew - m);
                s += p2;
                ph[4 + e] = (short)f2bfu(p2);
            }
            const int slot = (sub * 8 + c8) ^ (row & 7);
            *(s16x8*)(smem + row * 1024 + slot * 16) = ph;
        }
        s += __shfl_xor(s, 1);
        s += __shfl_xor(s, 2);
        s += __shfl_xor(s, 4);
        if (sub == 0) rowinvS[row] = 1.0f / s;
    }
    __syncthreads();   // P + rowinv ready; preloaded B landed

    // ---- PV GEMM: 16 K-steps, barrier-free, depth-2 reg pipeline (r9) ----
    f32x4 acc[4][2];
    #pragma unroll
    for (int rt = 0; rt < 4; ++rt)
        #pragma unroll
        for (int ct = 0; ct < 2; ++ct) acc[rt][ct] = f32x4{0.f,0.f,0.f,0.f};

    #pragma unroll
    for (int t = 0; t < 16; ++t) {
        const int cur = t % 3;
        if (t + 2 < 16) {
            const int nx = (t + 2) % 3;
            pb[nx][0] = *(const s16x8*)(gH0 + (t + 2) * 32);
            pb[nx][1] = *(const s16x8*)(gH1 + (t + 2) * 32);
            pb[nx][2] = *(const s16x8*)(gL0 + (t + 2) * 32);
            pb[nx][3] = *(const s16x8*)(gL1 + (t + 2) * 32);
        }
        s16x8 af[4];
        #pragma unroll
        for (int rt = 0; rt < 4; ++rt) {
            const int row = rt * 16 + fb;
            const unsigned seg = (unsigned)(t * 4 + g) ^ (unsigned)(row & 7);
            af[rt] = *(const s16x8*)(smem + (unsigned)(row * 1024) + seg * 16);
        }
        __builtin_amdgcn_s_setprio(1);
        #pragma unroll
        for (int rt = 0; rt < 4; ++rt) {
            acc[rt][0] = mfma16(af[rt], pb[cur][0], acc[rt][0]);
            acc[rt][0] = mfma16(af[rt], pb[cur][2], acc[rt][0]);
            acc[rt][1] = mfma16(af[rt], pb[cur][1], acc[rt][1]);
            acc[rt][1] = mfma16(af[rt], pb[cur][3], acc[rt][1]);
        }
        __builtin_amdgcn_s_setprio(0);
    }

    // epilogue: scale by rowinv, elu, store. D row = rt*16 + g*4 + r.
    #pragma unroll
    for (int rt = 0; rt < 4; ++rt) {
        float inv[4];
        #pragma unroll
        for (int r = 0; r < 4; ++r) inv[r] = rowinvS[rt * 16 + g * 4 + r];
        #pragma unroll
        for (int ct = 0; ct < 2; ++ct) {
            const int f = w * 32 + ct * 16 + fb;
            #pragma unroll
            for (int r = 0; r < 4; ++r) {
                float v = acc[rt][ct][r] * inv[r];
                v = (v > 0.f) ? v : expm1f(v);
                const size_t o = ((size_t)bn * NODES + i0 + rt * 16 + g * 4 + r) * FDIM + f;
                if (flag) ((float*)out)[o] = v;
                else      ((unsigned short*)out)[o] = f2bfu(v);
            }
        }
    }
}

extern "C" void kernel_launch(void* const* d_in, const int* in_sizes, int n_in,
                              void* d_out, int out_size, void* d_ws, size_t ws_size,
                              hipStream_t stream)
{
    const void* h   = d_in[0];
    const int*  adj = (const int*)d_in[1];
    const void* W   = d_in[2];
    const void* a   = d_in[3];

    // ws layout: flag 256B | src 128K | dst 128K | WtHi 128K | WtLo 128K
    //            | WhTHi 16.78M | WhTLo 16.78M   (~34.1 MB total)
    int*   flag  = (int*)d_ws;
    float* srcv  = (float*)d_ws + 64;
    float* dstv  = srcv + BN * NODES;
    short* WtHi  = (short*)(dstv + BN * NODES);
    short* WtLo  = WtHi + FDIM * FDIM;
    short* WhTHi = WtLo + FDIM * FDIM;
    short* WhTLo = WhTHi + (size_t)BN * FDIM * NODES;

    detect_kernel<<<1, 256, 0, stream>>>((const unsigned short*)h, flag);
    prep_w_kernel<<<dim3(16, 16), 256, 0, stream>>>(W, flag, WtHi, WtLo);
    wh_gemm<<<512, 512, 0, stream>>>(h, WtHi, WtLo, a, flag,
                                     WhTHi, WhTLo, srcv, dstv);
    pv_gemm<<<512, 512, 0, stream>>>(WhTHi, WhTLo, srcv, dstv, adj, flag, d_out);
}